// Round 2
// baseline (371.555 us; speedup 1.0000x reference)
//
#include <hip/hip_runtime.h>
#include <hip/hip_bf16.h>

typedef __hip_bfloat16 bf16;
typedef __attribute__((ext_vector_type(8))) short s8v;   // 8 bf16 = 16B
typedef __attribute__((ext_vector_type(4))) float f4v;   // MFMA accum

#define H_ 12
#define E_ 768
#define HD_ 64
#define B_ 8
#define S_ 512
#define M_ 4096   // B*S

struct P4 { const void* s[4]; bf16* d[4]; };
struct PV { const void* s[10]; bf16* d[10]; };

// ---------------- dtype detection ----------------
// If X is packed bf16, bits 7..14 of each u32 word are a bf16 exponent field
// (~[100,141] for N(0,1) data, ~99% of words). If X is fp32, those bits are
// uniform mantissa bits (~16% in range). flag: 0 = bf16 inputs, 1 = fp32.
__global__ void detect_kernel(const unsigned int* __restrict__ X, int* flag) {
    __shared__ int cnt;
    if (threadIdx.x == 0) cnt = 0;
    __syncthreads();
    int good = 0;
    for (int i = threadIdx.x; i < 16384; i += 256) {
        unsigned e = (X[i] >> 7) & 0xFFu;
        good += (e >= 100u && e <= 141u) ? 1 : 0;
    }
    atomicAdd(&cnt, good);
    __syncthreads();
    if (threadIdx.x == 0) *flag = (cnt > 9830) ? 0 : 1;  // 60% cut
}

__device__ __forceinline__ bf16 ldcvt(const void* s, int i, int fp32) {
    return fp32 ? __float2bfloat16(((const float*)s)[i]) : ((const bf16*)s)[i];
}

// convert two big activations (X, enc) to canonical bf16
__global__ void conv2_kernel(const void* s0, const void* s1, bf16* d0, bf16* d1,
                             int n, const int* __restrict__ flag) {
    int fp32 = *flag;
    const void* s = blockIdx.y ? s1 : s0;
    bf16* d = blockIdx.y ? d1 : d0;
    int i = blockIdx.x * 256 + threadIdx.x;
    if (i < n) d[i] = ldcvt(s, i, fp32);
}

// convert 10 small vectors (biases / ln params)
__global__ void convV_kernel(PV p, const int* __restrict__ flag) {
    int fp32 = *flag;
    const void* s = p.s[blockIdx.x];
    bf16* d = p.d[blockIdx.x];
    for (int i = threadIdx.x; i < E_; i += 256) d[i] = ldcvt(s, i, fp32);
}

// Bt[n][k], n = h*64+d, k = e  from w[h][e][d]   (4 tensors)
__global__ void permute4_kernel(P4 p, const int* __restrict__ flag) {
    int t = blockIdx.x * 256 + threadIdx.x;
    if (t >= H_ * E_ * HD_) return;
    int fp32 = *flag;
    const void* s = p.s[blockIdx.y];
    bf16* d = p.d[blockIdx.y];
    int n = t / E_, e = t % E_;
    int h = n >> 6, dd = n & 63;
    d[t] = ldcvt(s, (h * E_ + e) * HD_ + dd, fp32);
}

// Bt[n][k] = W[k][n]  (transpose 768x768, 4 tensors)
__global__ void transpose4_kernel(P4 p, const int* __restrict__ flag) {
    int t = blockIdx.x * 256 + threadIdx.x;
    if (t >= E_ * E_) return;
    int fp32 = *flag;
    const void* s = p.s[blockIdx.y];
    bf16* d = p.d[blockIdx.y];
    int n = t / E_, k = t % E_;
    d[t] = ldcvt(s, k * E_ + n, fp32);
}

// ---------------- GEMM: C[M,768] = A[M,768] * Bt[768,768]^T ----------------
// EPI 0: store   1: bias+residual   2: bias+gelu
template <int EPI>
__global__ __launch_bounds__(256) void gemm_bt(const bf16* __restrict__ A,
                                               const bf16* __restrict__ Bt,
                                               bf16* __restrict__ C,
                                               const bf16* __restrict__ bias,
                                               const bf16* __restrict__ res) {
    __shared__ short As[64 * 40];
    __shared__ short Bs[64 * 40];
    const int bm = blockIdx.x;
    const int bn = blockIdx.y;
    const int tid = threadIdx.x;
    const int w = tid >> 6, l = tid & 63;
    const int wm = (w >> 1) * 32, wn = (w & 1) * 32;
    const int r = tid >> 2, kc = (tid & 3) * 8;
    const int lr = (l >> 4) * 4, lc = l & 15, ko = (l >> 4) * 8;

    f4v acc[2][2] = {};
    const bf16* Ag = A + (size_t)(bm * 64 + r) * E_ + kc;
    const bf16* Bg = Bt + (size_t)(bn * 64 + r) * E_ + kc;

    for (int k0 = 0; k0 < E_; k0 += 32) {
        *(s8v*)&As[r * 40 + kc] = *(const s8v*)(Ag + k0);
        *(s8v*)&Bs[r * 40 + kc] = *(const s8v*)(Bg + k0);
        __syncthreads();
        s8v af0 = *(const s8v*)&As[(wm + lc) * 40 + ko];
        s8v af1 = *(const s8v*)&As[(wm + 16 + lc) * 40 + ko];
        s8v bf0 = *(const s8v*)&Bs[(wn + lc) * 40 + ko];
        s8v bf1 = *(const s8v*)&Bs[(wn + 16 + lc) * 40 + ko];
        acc[0][0] = __builtin_amdgcn_mfma_f32_16x16x32_bf16(af0, bf0, acc[0][0], 0, 0, 0);
        acc[0][1] = __builtin_amdgcn_mfma_f32_16x16x32_bf16(af0, bf1, acc[0][1], 0, 0, 0);
        acc[1][0] = __builtin_amdgcn_mfma_f32_16x16x32_bf16(af1, bf0, acc[1][0], 0, 0, 0);
        acc[1][1] = __builtin_amdgcn_mfma_f32_16x16x32_bf16(af1, bf1, acc[1][1], 0, 0, 0);
        __syncthreads();
    }

    for (int mt = 0; mt < 2; mt++)
        for (int nt = 0; nt < 2; nt++)
            for (int i = 0; i < 4; i++) {
                int row = bm * 64 + wm + mt * 16 + lr + i;
                int col = bn * 64 + wn + nt * 16 + lc;
                float v = acc[mt][nt][i];
                if (EPI == 1)
                    v += __bfloat162float(bias[col]) + __bfloat162float(res[(size_t)row * E_ + col]);
                if (EPI == 2) {
                    v += __bfloat162float(bias[col]);
                    v = 0.5f * v * (1.0f + erff(v * 0.70710678118654752f));
                }
                C[(size_t)row * E_ + col] = __float2bfloat16(v);
            }
}

// ---------------- fused flash attention (V == K per reference) ----------------
template <bool CAUSAL>
__global__ __launch_bounds__(256) void attn_kernel(const bf16* __restrict__ Q,
                                                   const bf16* __restrict__ Kx,
                                                   bf16* __restrict__ O,
                                                   const int* __restrict__ vlen) {
    __shared__ short qs[64 * 72];
    __shared__ short ks[64 * 72];
    __shared__ short kts[64 * 72];
    __shared__ short ps[64 * 72];

    const int idx = blockIdx.x;
    const int qt = idx & 7;
    const int bh = idx >> 3;
    const int h = bh % H_, b = bh / H_;
    const int tid = threadIdx.x, w = tid >> 6, l = tid & 63;
    const int lr = (l >> 4) * 4, lc = l & 15, ko = (l >> 4) * 8;

    for (int c = tid * 2; c < tid * 2 + 2; ++c) {
        int row = c >> 3, dc = (c & 7) * 8;
        const bf16* src = Q + (((size_t)(b * S_ + qt * 64 + row) * H_ + h) * HD_ + dc);
        *(s8v*)&qs[row * 72 + dc] = *(const s8v*)src;
    }

    const int valid = CAUSAL ? S_ : vlen[b];
    const int kmax = CAUSAL ? (qt + 1) : ((valid + 63) >> 6);

    float m_i[4], l_i[4];
    for (int i = 0; i < 4; i++) { m_i[i] = -3.0e38f; l_i[i] = 0.0f; }
    f4v o_acc[4] = {};
    __syncthreads();

    for (int kt = 0; kt < kmax; ++kt) {
        for (int c = tid * 2; c < tid * 2 + 2; ++c) {
            int row = c >> 3, dc = (c & 7) * 8;
            const bf16* src = Kx + (((size_t)(b * S_ + kt * 64 + row) * H_ + h) * HD_ + dc);
            s8v v = *(const s8v*)src;
            *(s8v*)&ks[row * 72 + dc] = v;
            #pragma unroll
            for (int j = 0; j < 8; j++) kts[(dc + j) * 72 + row] = v[j];
        }
        __syncthreads();

        f4v sacc[4] = {};
        s8v aq0 = *(const s8v*)&qs[(w * 16 + lc) * 72 + ko];
        s8v aq1 = *(const s8v*)&qs[(w * 16 + lc) * 72 + 32 + ko];
        #pragma unroll
        for (int nt = 0; nt < 4; nt++) {
            s8v bk0 = *(const s8v*)&ks[(nt * 16 + lc) * 72 + ko];
            s8v bk1 = *(const s8v*)&ks[(nt * 16 + lc) * 72 + 32 + ko];
            sacc[nt] = __builtin_amdgcn_mfma_f32_16x16x32_bf16(aq0, bk0, sacc[nt], 0, 0, 0);
            sacc[nt] = __builtin_amdgcn_mfma_f32_16x16x32_bf16(aq1, bk1, sacc[nt], 0, 0, 0);
        }

        #pragma unroll
        for (int i = 0; i < 4; i++) {
            int qabs = qt * 64 + w * 16 + lr + i;
            float sv[4];
            float mx = -3.0e38f;
            #pragma unroll
            for (int nt = 0; nt < 4; nt++) {
                int kabs = kt * 64 + nt * 16 + lc;
                float s = sacc[nt][i] * 0.125f;
                bool ok = CAUSAL ? (kabs <= qabs) : (kabs < valid);
                sv[nt] = ok ? s : -1.0e4f;
                mx = fmaxf(mx, sv[nt]);
            }
            #pragma unroll
            for (int off = 1; off < 16; off <<= 1) mx = fmaxf(mx, __shfl_xor(mx, off));
            float mnew = fmaxf(m_i[i], mx);
            float alpha = __expf(m_i[i] - mnew);
            float psum = 0.0f;
            #pragma unroll
            for (int nt = 0; nt < 4; nt++) {
                float p = __expf(sv[nt] - mnew);
                psum += p;
                *(bf16*)&ps[(w * 16 + lr + i) * 72 + nt * 16 + lc] = __float2bfloat16(p);
            }
            #pragma unroll
            for (int off = 1; off < 16; off <<= 1) psum += __shfl_xor(psum, off);
            l_i[i] = l_i[i] * alpha + psum;
            m_i[i] = mnew;
            #pragma unroll
            for (int dt = 0; dt < 4; dt++) o_acc[dt][i] *= alpha;
        }
        __syncthreads();

        s8v ap0 = *(const s8v*)&ps[(w * 16 + lc) * 72 + ko];
        s8v ap1 = *(const s8v*)&ps[(w * 16 + lc) * 72 + 32 + ko];
        #pragma unroll
        for (int dt = 0; dt < 4; dt++) {
            s8v bv0 = *(const s8v*)&kts[(dt * 16 + lc) * 72 + ko];
            s8v bv1 = *(const s8v*)&kts[(dt * 16 + lc) * 72 + 32 + ko];
            o_acc[dt] = __builtin_amdgcn_mfma_f32_16x16x32_bf16(ap0, bv0, o_acc[dt], 0, 0, 0);
            o_acc[dt] = __builtin_amdgcn_mfma_f32_16x16x32_bf16(ap1, bv1, o_acc[dt], 0, 0, 0);
        }
        __syncthreads();
    }

    #pragma unroll
    for (int dt = 0; dt < 4; dt++)
        #pragma unroll
        for (int i = 0; i < 4; i++) {
            int q = qt * 64 + w * 16 + lr + i;
            int d = dt * 16 + lc;
            float v = o_acc[dt][i] / l_i[i];
            O[((size_t)(b * S_ + q) * H_ + h) * HD_ + d] = __float2bfloat16(v);
        }
}

// ---------------- LayerNorm (optionally fp32 final store) ----------------
__global__ __launch_bounds__(256) void ln_kernel(const bf16* __restrict__ X,
                                                 const bf16* __restrict__ wv,
                                                 const bf16* __restrict__ bv,
                                                 bf16* __restrict__ outb,
                                                 float* __restrict__ outf,
                                                 const int* __restrict__ flag) {
    const int row = blockIdx.x;
    const int tid = threadIdx.x;
    const bf16* xr = X + (size_t)row * E_;
    float x0 = __bfloat162float(xr[tid]);
    float x1 = __bfloat162float(xr[tid + 256]);
    float x2 = __bfloat162float(xr[tid + 512]);
    float s = x0 + x1 + x2;
    float ss = x0 * x0 + x1 * x1 + x2 * x2;
    #pragma unroll
    for (int off = 32; off; off >>= 1) {
        s += __shfl_down(s, off);
        ss += __shfl_down(ss, off);
    }
    __shared__ float rs[4], rss[4];
    __shared__ float mu_s, rstd_s;
    if ((tid & 63) == 0) { rs[tid >> 6] = s; rss[tid >> 6] = ss; }
    __syncthreads();
    if (tid == 0) {
        float S = rs[0] + rs[1] + rs[2] + rs[3];
        float SS = rss[0] + rss[1] + rss[2] + rss[3];
        float mu = S * (1.0f / E_);
        float var = SS * (1.0f / E_) - mu * mu;
        mu_s = mu;
        rstd_s = rsqrtf(fmaxf(var, 0.0f) + 1e-12f);
    }
    __syncthreads();
    float mu = mu_s, rstd = rstd_s;
    const bool f32out = (outf != nullptr) && (*flag != 0);
    #pragma unroll
    for (int j = 0; j < 3; j++) {
        int c = tid + j * 256;
        float v = (((j == 0) ? x0 : (j == 1) ? x1 : x2) - mu) * rstd *
                      __bfloat162float(wv[c]) + __bfloat162float(bv[c]);
        if (f32out) outf[(size_t)row * E_ + c] = v;
        else        outb[(size_t)row * E_ + c] = __float2bfloat16(v);
    }
}

extern "C" void kernel_launch(void* const* d_in, const int* in_sizes, int n_in,
                              void* d_out, int out_size, void* d_ws, size_t ws_size,
                              hipStream_t stream) {
    const void* X = d_in[0];
    const void* enc = d_in[1];
    const int* vlen = (const int*)d_in[2];

    char* ws = (char*)d_ws;
    int* flag = (int*)ws;                            // 256 B reserved
    bf16* vecs = (bf16*)(ws + 256);                  // 10 x 768 bf16
    char* wbase = ws + 16384;
    const size_t WSZ = (size_t)E_ * E_ * sizeof(bf16);   // 1.125 MiB
    bf16* wk1 = (bf16*)(wbase + 0 * WSZ);
    bf16* wq1 = (bf16*)(wbase + 1 * WSZ);
    bf16* wk2 = (bf16*)(wbase + 2 * WSZ);
    bf16* wq2 = (bf16*)(wbase + 3 * WSZ);
    bf16* p1t = (bf16*)(wbase + 4 * WSZ);
    bf16* p2t = (bf16*)(wbase + 5 * WSZ);
    bf16* f1t = (bf16*)(wbase + 6 * WSZ);
    bf16* f2t = (bf16*)(wbase + 7 * WSZ);
    const size_t ASZ = (size_t)M_ * E_ * sizeof(bf16);   // 6 MiB
    char* abase = wbase + 8 * WSZ;
    bf16* Xc  = (bf16*)(abase + 0 * ASZ);
    bf16* ENCc = (bf16*)(abase + 1 * ASZ);
    bf16* A0 = (bf16*)(abase + 2 * ASZ);
    bf16* A1 = (bf16*)(abase + 3 * ASZ);
    bf16* A2 = (bf16*)(abase + 4 * ASZ);
    bf16* A3 = (bf16*)(abase + 5 * ASZ);

    bf16* bias1 = vecs + 0 * E_;  // proj1_b
    bf16* lw1   = vecs + 1 * E_;
    bf16* lb1   = vecs + 2 * E_;
    bf16* bias2 = vecs + 3 * E_;  // proj2_b
    bf16* lw2   = vecs + 4 * E_;
    bf16* lb2   = vecs + 5 * E_;
    bf16* fb1   = vecs + 6 * E_;
    bf16* fb2   = vecs + 7 * E_;
    bf16* lw3   = vecs + 8 * E_;
    bf16* lb3   = vecs + 9 * E_;

    detect_kernel<<<1, 256, 0, stream>>>((const unsigned int*)X, flag);

    conv2_kernel<<<dim3((M_ * E_ + 255) / 256, 2), 256, 0, stream>>>(X, enc, Xc, ENCc, M_ * E_, flag);

    PV pv;
    pv.s[0] = d_in[6];  pv.d[0] = bias1;
    pv.s[1] = d_in[7];  pv.d[1] = lw1;
    pv.s[2] = d_in[8];  pv.d[2] = lb1;
    pv.s[3] = d_in[12]; pv.d[3] = bias2;
    pv.s[4] = d_in[13]; pv.d[4] = lw2;
    pv.s[5] = d_in[14]; pv.d[5] = lb2;
    pv.s[6] = d_in[16]; pv.d[6] = fb1;
    pv.s[7] = d_in[18]; pv.d[7] = fb2;
    pv.s[8] = d_in[19]; pv.d[8] = lw3;
    pv.s[9] = d_in[20]; pv.d[9] = lb3;
    convV_kernel<<<10, 256, 0, stream>>>(pv, flag);

    P4 pk;
    pk.s[0] = d_in[3];  pk.d[0] = wk1;
    pk.s[1] = d_in[4];  pk.d[1] = wq1;
    pk.s[2] = d_in[9];  pk.d[2] = wk2;
    pk.s[3] = d_in[10]; pk.d[3] = wq2;
    permute4_kernel<<<dim3((H_ * E_ * HD_ + 255) / 256, 4), 256, 0, stream>>>(pk, flag);

    P4 pt;
    pt.s[0] = d_in[5];  pt.d[0] = p1t;
    pt.s[1] = d_in[11]; pt.d[1] = p2t;
    pt.s[2] = d_in[15]; pt.d[2] = f1t;
    pt.s[3] = d_in[17]; pt.d[3] = f2t;
    transpose4_kernel<<<dim3((E_ * E_ + 255) / 256, 4), 256, 0, stream>>>(pt, flag);

    dim3 gg(64, 12);
    // self-attention block
    gemm_bt<0><<<gg, 256, 0, stream>>>(Xc, wk1, A0, nullptr, nullptr);     // kx1
    gemm_bt<0><<<gg, 256, 0, stream>>>(Xc, wq1, A1, nullptr, nullptr);     // qx1
    attn_kernel<true><<<B_ * H_ * (S_ / 64), 256, 0, stream>>>(A1, A0, A2, nullptr);
    gemm_bt<1><<<gg, 256, 0, stream>>>(A2, p1t, A3, bias1, Xc);            // X2 + X
    ln_kernel<<<M_, 256, 0, stream>>>(A3, lw1, lb1, A0, nullptr, flag);    // Y -> A0
    // cross-attention block
    gemm_bt<0><<<gg, 256, 0, stream>>>(ENCc, wk2, A1, nullptr, nullptr);   // kx2
    gemm_bt<0><<<gg, 256, 0, stream>>>(A0, wq2, A2, nullptr, nullptr);     // qx2
    attn_kernel<false><<<B_ * H_ * (S_ / 64), 256, 0, stream>>>(A2, A1, A3, vlen);
    gemm_bt<1><<<gg, 256, 0, stream>>>(A3, p2t, A1, bias2, A0);            // Y2 + Y
    ln_kernel<<<M_, 256, 0, stream>>>(A1, lw2, lb2, A2, nullptr, flag);    // Z -> A2
    // FFN
    gemm_bt<2><<<gg, 256, 0, stream>>>(A2, f1t, A3, fb1, nullptr);         // gelu
    gemm_bt<1><<<gg, 256, 0, stream>>>(A3, f2t, A1, fb2, A2);              // F + Z
    ln_kernel<<<M_, 256, 0, stream>>>(A1, lw3, lb3, (bf16*)d_out, (float*)d_out, flag);
}

// Round 3
// 330.606 us; speedup vs baseline: 1.1239x; 1.1239x over previous
//
#include <hip/hip_runtime.h>
#include <hip/hip_bf16.h>

typedef __hip_bfloat16 bf16;
typedef __attribute__((ext_vector_type(8))) short s8v;   // 8 bf16 = 16B
typedef __attribute__((ext_vector_type(4))) short s4v;   // 4 bf16 = 8B
typedef __attribute__((ext_vector_type(4))) float f4v;   // MFMA accum

#define H_ 12
#define E_ 768
#define HD_ 64
#define B_ 8
#define S_ 512
#define M_ 4096   // B*S

struct P4 { const void* s[4]; bf16* d[4]; };
struct PV { const void* s[10]; bf16* d[10]; };

typedef __attribute__((address_space(3))) void lds_void;
typedef const __attribute__((address_space(1))) void g_void;

__device__ __forceinline__ void async_copy16(const bf16* g, short* l) {
    __builtin_amdgcn_global_load_lds((g_void*)g, (lds_void*)l, 16, 0, 0);
}

// ---------------- dtype detection (unchanged, verified r2) ----------------
__global__ void detect_kernel(const unsigned int* __restrict__ X, int* flag) {
    __shared__ int cnt;
    if (threadIdx.x == 0) cnt = 0;
    __syncthreads();
    int good = 0;
    for (int i = threadIdx.x; i < 16384; i += 256) {
        unsigned e = (X[i] >> 7) & 0xFFu;
        good += (e >= 100u && e <= 141u) ? 1 : 0;
    }
    atomicAdd(&cnt, good);
    __syncthreads();
    if (threadIdx.x == 0) *flag = (cnt > 9830) ? 0 : 1;
}

// ---------------- big activation convert (vectorized) ----------------
__global__ void conv2_kernel(const void* s0, const void* s1, bf16* d0, bf16* d1,
                             const int* __restrict__ flag) {
    const int fp32 = *flag;
    const void* s = blockIdx.y ? s1 : s0;
    bf16* d = blockIdx.y ? d1 : d0;
    int i = (blockIdx.x * 256 + threadIdx.x) * 4;
    if (fp32) {
        float4 v = *(const float4*)((const float*)s + i);
        bf16 a = __float2bfloat16(v.x), b = __float2bfloat16(v.y),
             c = __float2bfloat16(v.z), e = __float2bfloat16(v.w);
        s4v o = { *(short*)&a, *(short*)&b, *(short*)&c, *(short*)&e };
        *(s4v*)(d + i) = o;
    } else {
        *(s4v*)(d + i) = *(const s4v*)((const bf16*)s + i);
    }
}

// ---------------- small vector convert ----------------
__device__ __forceinline__ bf16 ldcvt(const void* s, int i, int fp32) {
    return fp32 ? __float2bfloat16(((const float*)s)[i]) : ((const bf16*)s)[i];
}

__global__ void convV_kernel(PV p, const int* __restrict__ flag) {
    int fp32 = *flag;
    const void* s = p.s[blockIdx.x];
    bf16* d = p.d[blockIdx.x];
    for (int i = threadIdx.x; i < E_; i += 256) d[i] = ldcvt(s, i, fp32);
}

// ---- Bt[n=h*64+d][e] from w[h][e][d]: per-h [E][64]->[64][E] LDS transpose ----
__global__ void permute4_kernel(P4 p, const int* __restrict__ flag) {
    __shared__ float t[64][65];
    const int fp32 = *flag;
    const void* s = p.s[blockIdx.z];
    bf16* d = p.d[blockIdx.z];
    const int e0 = blockIdx.x * 64, h = blockIdx.y;
    const int c = threadIdx.x & 63, r0 = threadIdx.x >> 6;
    #pragma unroll
    for (int j = 0; j < 16; ++j) {
        int r = r0 * 16 + j;                       // e within tile
        int idx = (h * E_ + e0 + r) * HD_ + c;     // d = c (coalesced)
        t[r][c] = fp32 ? ((const float*)s)[idx] : __bfloat162float(((const bf16*)s)[idx]);
    }
    __syncthreads();
    #pragma unroll
    for (int j = 0; j < 16; ++j) {
        int r = r0 * 16 + j;                       // d within tile
        d[(size_t)(h * 64 + r) * E_ + e0 + c] = __float2bfloat16(t[c][r]);
    }
}

// ---- Bt[n][k] = W[k][n]: 64x64 LDS-tiled transpose ----
__global__ void transpose4_kernel(P4 p, const int* __restrict__ flag) {
    __shared__ float t[64][65];
    const int fp32 = *flag;
    const void* s = p.s[blockIdx.z];
    bf16* d = p.d[blockIdx.z];
    const int k0 = blockIdx.x * 64, n0 = blockIdx.y * 64;
    const int c = threadIdx.x & 63, r0 = threadIdx.x >> 6;
    #pragma unroll
    for (int j = 0; j < 16; ++j) {
        int r = r0 * 16 + j;
        int idx = (k0 + r) * E_ + n0 + c;          // coalesced read
        t[r][c] = fp32 ? ((const float*)s)[idx] : __bfloat162float(((const bf16*)s)[idx]);
    }
    __syncthreads();
    #pragma unroll
    for (int j = 0; j < 16; ++j) {
        int r = r0 * 16 + j;
        d[(size_t)(n0 + r) * E_ + k0 + c] = __float2bfloat16(t[c][r]);  // coalesced write
    }
}

// ---------------- GEMM v2: C[M,N] = A[M,768] * Bt[N,768]^T ----------------
// 128x64 tile, BK=64, global_load_lds(16B) staging, XOR-8 chunk swizzle.
// EPI 0: store  1: bias+residual  2: bias+gelu  3: split store (col<768 -> C, else C2)
template <int EPI>
__global__ __launch_bounds__(256, 4) void gemm2(const bf16* __restrict__ A,
                                                const bf16* __restrict__ Bt,
                                                bf16* __restrict__ C,
                                                bf16* __restrict__ C2,
                                                const bf16* __restrict__ bias,
                                                const bf16* __restrict__ res) {
    __shared__ short As[128 * 64];   // [row][chunk^(row&7) swizzled], 16 KB
    __shared__ short Bs[64 * 64];    // 8 KB
    const int bm = blockIdx.x, bn = blockIdx.y;
    const int tid = threadIdx.x;
    const int w = tid >> 6, l = tid & 63;
    const int wr = w >> 1, wc = w & 1;
    const int lc = l & 15, quad = l >> 4;
    const int srA = l >> 3, slot = l & 7;        // staging: 8 lanes/row, 16B chunks

    f4v acc[4][2] = {};

    for (int k0 = 0; k0 < E_; k0 += 64) {
        #pragma unroll
        for (int c = 0; c < 4; ++c) {            // A: 16 wave-segments of 1 KB
            int seg = w * 4 + c;
            int row = seg * 8 + srA;
            int kc = (slot ^ srA) * 8;           // row&7 == srA
            async_copy16(A + (size_t)(bm * 128 + row) * E_ + k0 + kc, &As[seg * 512]);
        }
        #pragma unroll
        for (int c = 0; c < 2; ++c) {            // B: 8 wave-segments
            int seg = w * 2 + c;
            int row = seg * 8 + srA;
            int kc = (slot ^ srA) * 8;
            async_copy16(Bt + (size_t)(bn * 64 + row) * E_ + k0 + kc, &Bs[seg * 512]);
        }
        __syncthreads();

        #pragma unroll
        for (int kk = 0; kk < 2; ++kk) {
            s8v b[2];
            #pragma unroll
            for (int nt = 0; nt < 2; ++nt) {
                int col = wc * 32 + nt * 16 + lc;
                b[nt] = *(const s8v*)&Bs[col * 64 + (((kk * 4 + quad) ^ (col & 7)) * 8)];
            }
            #pragma unroll
            for (int mt = 0; mt < 4; ++mt) {
                int row = wr * 64 + mt * 16 + lc;
                s8v a = *(const s8v*)&As[row * 64 + (((kk * 4 + quad) ^ (row & 7)) * 8)];
                acc[mt][0] = __builtin_amdgcn_mfma_f32_16x16x32_bf16(a, b[0], acc[mt][0], 0, 0, 0);
                acc[mt][1] = __builtin_amdgcn_mfma_f32_16x16x32_bf16(a, b[1], acc[mt][1], 0, 0, 0);
            }
        }
        __syncthreads();
    }

    #pragma unroll
    for (int mt = 0; mt < 4; ++mt)
        #pragma unroll
        for (int nt = 0; nt < 2; ++nt)
            #pragma unroll
            for (int i = 0; i < 4; ++i) {
                int row = bm * 128 + wr * 64 + mt * 16 + quad * 4 + i;
                int col = bn * 64 + wc * 32 + nt * 16 + lc;
                float v = acc[mt][nt][i];
                if (EPI == 1)
                    v += __bfloat162float(bias[col]) + __bfloat162float(res[(size_t)row * E_ + col]);
                if (EPI == 2) {
                    v += __bfloat162float(bias[col]);
                    v = 0.5f * v * (1.0f + erff(v * 0.70710678118654752f));
                }
                if (EPI == 3) {
                    if (col < E_) C[(size_t)row * E_ + col] = __float2bfloat16(v);
                    else          C2[(size_t)row * E_ + (col - E_)] = __float2bfloat16(v);
                } else {
                    C[(size_t)row * E_ + col] = __float2bfloat16(v);
                }
            }
}

// ---------------- fused flash attention (unchanged, verified r2) ----------------
template <bool CAUSAL>
__global__ __launch_bounds__(256) void attn_kernel(const bf16* __restrict__ Q,
                                                   const bf16* __restrict__ Kx,
                                                   bf16* __restrict__ O,
                                                   const int* __restrict__ vlen) {
    __shared__ short qs[64 * 72];
    __shared__ short ks[64 * 72];
    __shared__ short kts[64 * 72];
    __shared__ short ps[64 * 72];

    const int idx = blockIdx.x;
    const int qt = idx & 7;
    const int bh = idx >> 3;
    const int h = bh % H_, b = bh / H_;
    const int tid = threadIdx.x, w = tid >> 6, l = tid & 63;
    const int lr = (l >> 4) * 4, lc = l & 15, ko = (l >> 4) * 8;

    for (int c = tid * 2; c < tid * 2 + 2; ++c) {
        int row = c >> 3, dc = (c & 7) * 8;
        const bf16* src = Q + (((size_t)(b * S_ + qt * 64 + row) * H_ + h) * HD_ + dc);
        *(s8v*)&qs[row * 72 + dc] = *(const s8v*)src;
    }

    const int valid = CAUSAL ? S_ : vlen[b];
    const int kmax = CAUSAL ? (qt + 1) : ((valid + 63) >> 6);

    float m_i[4], l_i[4];
    for (int i = 0; i < 4; i++) { m_i[i] = -3.0e38f; l_i[i] = 0.0f; }
    f4v o_acc[4] = {};
    __syncthreads();

    for (int kt = 0; kt < kmax; ++kt) {
        for (int c = tid * 2; c < tid * 2 + 2; ++c) {
            int row = c >> 3, dc = (c & 7) * 8;
            const bf16* src = Kx + (((size_t)(b * S_ + kt * 64 + row) * H_ + h) * HD_ + dc);
            s8v v = *(const s8v*)src;
            *(s8v*)&ks[row * 72 + dc] = v;
            #pragma unroll
            for (int j = 0; j < 8; j++) kts[(dc + j) * 72 + row] = v[j];
        }
        __syncthreads();

        f4v sacc[4] = {};
        s8v aq0 = *(const s8v*)&qs[(w * 16 + lc) * 72 + ko];
        s8v aq1 = *(const s8v*)&qs[(w * 16 + lc) * 72 + 32 + ko];
        #pragma unroll
        for (int nt = 0; nt < 4; nt++) {
            s8v bk0 = *(const s8v*)&ks[(nt * 16 + lc) * 72 + ko];
            s8v bk1 = *(const s8v*)&ks[(nt * 16 + lc) * 72 + 32 + ko];
            sacc[nt] = __builtin_amdgcn_mfma_f32_16x16x32_bf16(aq0, bk0, sacc[nt], 0, 0, 0);
            sacc[nt] = __builtin_amdgcn_mfma_f32_16x16x32_bf16(aq1, bk1, sacc[nt], 0, 0, 0);
        }

        #pragma unroll
        for (int i = 0; i < 4; i++) {
            int qabs = qt * 64 + w * 16 + lr + i;
            float sv[4];
            float mx = -3.0e38f;
            #pragma unroll
            for (int nt = 0; nt < 4; nt++) {
                int kabs = kt * 64 + nt * 16 + lc;
                float s = sacc[nt][i] * 0.125f;
                bool ok = CAUSAL ? (kabs <= qabs) : (kabs < valid);
                sv[nt] = ok ? s : -1.0e4f;
                mx = fmaxf(mx, sv[nt]);
            }
            #pragma unroll
            for (int off = 1; off < 16; off <<= 1) mx = fmaxf(mx, __shfl_xor(mx, off));
            float mnew = fmaxf(m_i[i], mx);
            float alpha = __expf(m_i[i] - mnew);
            float psum = 0.0f;
            #pragma unroll
            for (int nt = 0; nt < 4; nt++) {
                float p = __expf(sv[nt] - mnew);
                psum += p;
                *(bf16*)&ps[(w * 16 + lr + i) * 72 + nt * 16 + lc] = __float2bfloat16(p);
            }
            #pragma unroll
            for (int off = 1; off < 16; off <<= 1) psum += __shfl_xor(psum, off);
            l_i[i] = l_i[i] * alpha + psum;
            m_i[i] = mnew;
            #pragma unroll
            for (int dt = 0; dt < 4; dt++) o_acc[dt][i] *= alpha;
        }
        __syncthreads();

        s8v ap0 = *(const s8v*)&ps[(w * 16 + lc) * 72 + ko];
        s8v ap1 = *(const s8v*)&ps[(w * 16 + lc) * 72 + 32 + ko];
        #pragma unroll
        for (int dt = 0; dt < 4; dt++) {
            s8v bv0 = *(const s8v*)&kts[(dt * 16 + lc) * 72 + ko];
            s8v bv1 = *(const s8v*)&kts[(dt * 16 + lc) * 72 + 32 + ko];
            o_acc[dt] = __builtin_amdgcn_mfma_f32_16x16x32_bf16(ap0, bv0, o_acc[dt], 0, 0, 0);
            o_acc[dt] = __builtin_amdgcn_mfma_f32_16x16x32_bf16(ap1, bv1, o_acc[dt], 0, 0, 0);
        }
        __syncthreads();
    }

    #pragma unroll
    for (int dt = 0; dt < 4; dt++)
        #pragma unroll
        for (int i = 0; i < 4; i++) {
            int q = qt * 64 + w * 16 + lr + i;
            int d = dt * 16 + lc;
            float v = o_acc[dt][i] / l_i[i];
            O[((size_t)(b * S_ + q) * H_ + h) * HD_ + d] = __float2bfloat16(v);
        }
}

// ---------------- LayerNorm (unchanged, verified r2) ----------------
__global__ __launch_bounds__(256) void ln_kernel(const bf16* __restrict__ X,
                                                 const bf16* __restrict__ wv,
                                                 const bf16* __restrict__ bv,
                                                 bf16* __restrict__ outb,
                                                 float* __restrict__ outf,
                                                 const int* __restrict__ flag) {
    const int row = blockIdx.x;
    const int tid = threadIdx.x;
    const bf16* xr = X + (size_t)row * E_;
    float x0 = __bfloat162float(xr[tid]);
    float x1 = __bfloat162float(xr[tid + 256]);
    float x2 = __bfloat162float(xr[tid + 512]);
    float s = x0 + x1 + x2;
    float ss = x0 * x0 + x1 * x1 + x2 * x2;
    #pragma unroll
    for (int off = 32; off; off >>= 1) {
        s += __shfl_down(s, off);
        ss += __shfl_down(ss, off);
    }
    __shared__ float rs[4], rss[4];
    __shared__ float mu_s, rstd_s;
    if ((tid & 63) == 0) { rs[tid >> 6] = s; rss[tid >> 6] = ss; }
    __syncthreads();
    if (tid == 0) {
        float S = rs[0] + rs[1] + rs[2] + rs[3];
        float SS = rss[0] + rss[1] + rss[2] + rss[3];
        float mu = S * (1.0f / E_);
        float var = SS * (1.0f / E_) - mu * mu;
        mu_s = mu;
        rstd_s = rsqrtf(fmaxf(var, 0.0f) + 1e-12f);
    }
    __syncthreads();
    float mu = mu_s, rstd = rstd_s;
    const bool f32out = (outf != nullptr) && (*flag != 0);
    #pragma unroll
    for (int j = 0; j < 3; j++) {
        int c = tid + j * 256;
        float v = (((j == 0) ? x0 : (j == 1) ? x1 : x2) - mu) * rstd *
                      __bfloat162float(wv[c]) + __bfloat162float(bv[c]);
        if (f32out) outf[(size_t)row * E_ + c] = v;
        else        outb[(size_t)row * E_ + c] = __float2bfloat16(v);
    }
}

extern "C" void kernel_launch(void* const* d_in, const int* in_sizes, int n_in,
                              void* d_out, int out_size, void* d_ws, size_t ws_size,
                              hipStream_t stream) {
    const void* X = d_in[0];
    const void* enc = d_in[1];
    const int* vlen = (const int*)d_in[2];

    char* ws = (char*)d_ws;
    int* flag = (int*)ws;
    bf16* vecs = (bf16*)(ws + 256);
    char* wbase = ws + 16384;
    const size_t WSZ = (size_t)E_ * E_ * sizeof(bf16);
    bf16* wk1 = (bf16*)(wbase + 0 * WSZ);   // wk1|wq1 contiguous = N=1536 Bt
    bf16* wq1 = (bf16*)(wbase + 1 * WSZ);
    bf16* wk2 = (bf16*)(wbase + 2 * WSZ);
    bf16* wq2 = (bf16*)(wbase + 3 * WSZ);
    bf16* p1t = (bf16*)(wbase + 4 * WSZ);
    bf16* p2t = (bf16*)(wbase + 5 * WSZ);
    bf16* f1t = (bf16*)(wbase + 6 * WSZ);
    bf16* f2t = (bf16*)(wbase + 7 * WSZ);
    const size_t ASZ = (size_t)M_ * E_ * sizeof(bf16);
    char* abase = wbase + 8 * WSZ;
    bf16* Xc   = (bf16*)(abase + 0 * ASZ);
    bf16* ENCc = (bf16*)(abase + 1 * ASZ);
    bf16* A0 = (bf16*)(abase + 2 * ASZ);
    bf16* A1 = (bf16*)(abase + 3 * ASZ);
    bf16* A2 = (bf16*)(abase + 4 * ASZ);
    bf16* A3 = (bf16*)(abase + 5 * ASZ);

    bf16* bias1 = vecs + 0 * E_;
    bf16* lw1   = vecs + 1 * E_;
    bf16* lb1   = vecs + 2 * E_;
    bf16* bias2 = vecs + 3 * E_;
    bf16* lw2   = vecs + 4 * E_;
    bf16* lb2   = vecs + 5 * E_;
    bf16* fb1   = vecs + 6 * E_;
    bf16* fb2   = vecs + 7 * E_;
    bf16* lw3   = vecs + 8 * E_;
    bf16* lb3   = vecs + 9 * E_;

    detect_kernel<<<1, 256, 0, stream>>>((const unsigned int*)X, flag);

    conv2_kernel<<<dim3(M_ * E_ / 1024, 2), 256, 0, stream>>>(X, enc, Xc, ENCc, flag);

    PV pv;
    pv.s[0] = d_in[6];  pv.d[0] = bias1;
    pv.s[1] = d_in[7];  pv.d[1] = lw1;
    pv.s[2] = d_in[8];  pv.d[2] = lb1;
    pv.s[3] = d_in[12]; pv.d[3] = bias2;
    pv.s[4] = d_in[13]; pv.d[4] = lw2;
    pv.s[5] = d_in[14]; pv.d[5] = lb2;
    pv.s[6] = d_in[16]; pv.d[6] = fb1;
    pv.s[7] = d_in[18]; pv.d[7] = fb2;
    pv.s[8] = d_in[19]; pv.d[8] = lw3;
    pv.s[9] = d_in[20]; pv.d[9] = lb3;
    convV_kernel<<<10, 256, 0, stream>>>(pv, flag);

    P4 pk;
    pk.s[0] = d_in[3];  pk.d[0] = wk1;
    pk.s[1] = d_in[4];  pk.d[1] = wq1;
    pk.s[2] = d_in[9];  pk.d[2] = wk2;
    pk.s[3] = d_in[10]; pk.d[3] = wq2;
    permute4_kernel<<<dim3(12, 12, 4), 256, 0, stream>>>(pk, flag);

    P4 pt;
    pt.s[0] = d_in[5];  pt.d[0] = p1t;
    pt.s[1] = d_in[11]; pt.d[1] = p2t;
    pt.s[2] = d_in[15]; pt.d[2] = f1t;
    pt.s[3] = d_in[17]; pt.d[3] = f2t;
    transpose4_kernel<<<dim3(12, 12, 4), 256, 0, stream>>>(pt, flag);

    // self-attention block
    gemm2<3><<<dim3(32, 24), 256, 0, stream>>>(Xc, wk1, A0, A1, nullptr, nullptr);  // kx1->A0, qx1->A1
    attn_kernel<true><<<B_ * H_ * (S_ / 64), 256, 0, stream>>>(A1, A0, A2, nullptr);
    gemm2<1><<<dim3(32, 12), 256, 0, stream>>>(A2, p1t, A3, nullptr, bias1, Xc);    // X2 + X
    ln_kernel<<<M_, 256, 0, stream>>>(A3, lw1, lb1, A0, nullptr, flag);             // Y -> A0
    // cross-attention block
    gemm2<0><<<dim3(32, 12), 256, 0, stream>>>(ENCc, wk2, A1, nullptr, nullptr, nullptr);
    gemm2<0><<<dim3(32, 12), 256, 0, stream>>>(A0, wq2, A2, nullptr, nullptr, nullptr);
    attn_kernel<false><<<B_ * H_ * (S_ / 64), 256, 0, stream>>>(A2, A1, A3, vlen);
    gemm2<1><<<dim3(32, 12), 256, 0, stream>>>(A3, p2t, A1, nullptr, bias2, A0);    // Y2 + Y
    ln_kernel<<<M_, 256, 0, stream>>>(A1, lw2, lb2, A2, nullptr, flag);             // Z -> A2
    // FFN
    gemm2<2><<<dim3(32, 12), 256, 0, stream>>>(A2, f1t, A3, nullptr, fb1, nullptr); // gelu
    gemm2<1><<<dim3(32, 12), 256, 0, stream>>>(A3, f2t, A1, nullptr, fb2, A2);      // F + Z
    ln_kernel<<<M_, 256, 0, stream>>>(A1, lw3, lb3, (bf16*)d_out, (float*)d_out, flag);
}

// Round 5
// 303.579 us; speedup vs baseline: 1.2239x; 1.0890x over previous
//
#include <hip/hip_runtime.h>
#include <hip/hip_bf16.h>

typedef __hip_bfloat16 bf16;
typedef __attribute__((ext_vector_type(8))) short s8v;   // 8 bf16 = 16B
typedef __attribute__((ext_vector_type(4))) short s4v;   // 4 bf16 = 8B
typedef __attribute__((ext_vector_type(4))) float f4v;   // MFMA accum

#define H_ 12
#define E_ 768
#define HD_ 64
#define B_ 8
#define S_ 512
#define M_ 4096   // B*S

struct P9 { const void* s[8]; bf16* d[8]; const void* vs[10]; bf16* vd[10]; };

typedef __attribute__((address_space(3))) void lds_void;
typedef const __attribute__((address_space(1))) void g_void;

__device__ __forceinline__ void async_copy16(const bf16* g, short* l) {
    __builtin_amdgcn_global_load_lds((g_void*)g, (lds_void*)l, 16, 0, 0);
}

// exact bf16(packed in short) -> f32
__device__ __forceinline__ float sh2f(short v) {
    unsigned int u = ((unsigned int)(unsigned short)v) << 16;
    return __uint_as_float(u);
}

// ---------------- dtype detection (verified r2/r3) ----------------
__global__ void detect_kernel(const unsigned int* __restrict__ X, int* flag) {
    __shared__ int cnt;
    if (threadIdx.x == 0) cnt = 0;
    __syncthreads();
    int good = 0;
    for (int i = threadIdx.x; i < 16384; i += 256) {
        unsigned e = (X[i] >> 7) & 0xFFu;
        good += (e >= 100u && e <= 141u) ? 1 : 0;
    }
    atomicAdd(&cnt, good);
    __syncthreads();
    if (threadIdx.x == 0) *flag = (cnt > 9830) ? 0 : 1;
}

// ---------------- big activation convert (verified r3) ----------------
__global__ void conv2_kernel(const void* s0, const void* s1, bf16* d0, bf16* d1,
                             const int* __restrict__ flag) {
    const int fp32 = *flag;
    const void* s = blockIdx.y ? s1 : s0;
    bf16* d = blockIdx.y ? d1 : d0;
    int i = (blockIdx.x * 256 + threadIdx.x) * 4;
    if (fp32) {
        float4 v = *(const float4*)((const float*)s + i);
        bf16 a = __float2bfloat16(v.x), b = __float2bfloat16(v.y),
             c = __float2bfloat16(v.z), e = __float2bfloat16(v.w);
        s4v o = { *(short*)&a, *(short*)&b, *(short*)&c, *(short*)&e };
        *(s4v*)(d + i) = o;
    } else {
        *(s4v*)(d + i) = *(const s4v*)((const bf16*)s + i);
    }
}

__device__ __forceinline__ bf16 ldcvt(const void* s, int i, int fp32) {
    return fp32 ? __float2bfloat16(((const float*)s)[i]) : ((const bf16*)s)[i];
}

// ---- merged weight repack: z<4 permute [H,E,64]->[n=h*64+d][e];
//      z in 4..7 transpose 768x768; z==8 small vectors ----
__global__ void repack_kernel(P9 p, const int* __restrict__ flag) {
    const int fp32 = *flag;
    const int z = blockIdx.z;
    if (z == 8) {
        int id = blockIdx.y * 12 + blockIdx.x;
        if (id < 10) {
            const void* s = p.vs[id];
            bf16* d = p.vd[id];
            for (int i = threadIdx.x; i < E_; i += 256) d[i] = ldcvt(s, i, fp32);
        }
        return;
    }
    __shared__ float t[64][65];
    const int c = threadIdx.x & 63, r0 = threadIdx.x >> 6;
    if (z < 4) {
        const void* s = p.s[z];
        bf16* d = p.d[z];
        const int e0 = blockIdx.x * 64, h = blockIdx.y;
        #pragma unroll
        for (int j = 0; j < 16; ++j) {
            int r = r0 * 16 + j;
            int idx = (h * E_ + e0 + r) * HD_ + c;
            t[r][c] = fp32 ? ((const float*)s)[idx] : __bfloat162float(((const bf16*)s)[idx]);
        }
        __syncthreads();
        #pragma unroll
        for (int j = 0; j < 16; ++j) {
            int r = r0 * 16 + j;
            d[(size_t)(h * 64 + r) * E_ + e0 + c] = __float2bfloat16(t[c][r]);
        }
    } else {
        const void* s = p.s[z];
        bf16* d = p.d[z];
        const int k0 = blockIdx.x * 64, n0 = blockIdx.y * 64;
        #pragma unroll
        for (int j = 0; j < 16; ++j) {
            int r = r0 * 16 + j;
            int idx = (k0 + r) * E_ + n0 + c;
            t[r][c] = fp32 ? ((const float*)s)[idx] : __bfloat162float(((const bf16*)s)[idx]);
        }
        __syncthreads();
        #pragma unroll
        for (int j = 0; j < 16; ++j) {
            int r = r0 * 16 + j;
            d[(size_t)(n0 + r) * E_ + k0 + c] = __float2bfloat16(t[c][r]);
        }
    }
}

// ---------------- GEMM v2: 128x64 tile (verified r3) — used for fused QKV ----------------
// EPI 3: split store (col<768 -> C, else C2)
template <int EPI>
__global__ __launch_bounds__(256, 4) void gemm2(const bf16* __restrict__ A,
                                                const bf16* __restrict__ Bt,
                                                bf16* __restrict__ C,
                                                bf16* __restrict__ C2,
                                                const bf16* __restrict__ bias,
                                                const bf16* __restrict__ res) {
    __shared__ short As[128 * 64];
    __shared__ short Bs[64 * 64];
    const int bm = blockIdx.x, bn = blockIdx.y;
    const int tid = threadIdx.x;
    const int w = tid >> 6, l = tid & 63;
    const int wr = w >> 1, wc = w & 1;
    const int lc = l & 15, quad = l >> 4;
    const int srA = l >> 3, slot = l & 7;

    f4v acc[4][2] = {};

    for (int k0 = 0; k0 < E_; k0 += 64) {
        #pragma unroll
        for (int c = 0; c < 4; ++c) {
            int seg = w * 4 + c;
            int row = seg * 8 + srA;
            int kc = (slot ^ srA) * 8;
            async_copy16(A + (size_t)(bm * 128 + row) * E_ + k0 + kc, &As[seg * 512]);
        }
        #pragma unroll
        for (int c = 0; c < 2; ++c) {
            int seg = w * 2 + c;
            int row = seg * 8 + srA;
            int kc = (slot ^ srA) * 8;
            async_copy16(Bt + (size_t)(bn * 64 + row) * E_ + k0 + kc, &Bs[seg * 512]);
        }
        __syncthreads();

        #pragma unroll
        for (int kk = 0; kk < 2; ++kk) {
            s8v b[2];
            #pragma unroll
            for (int nt = 0; nt < 2; ++nt) {
                int col = wc * 32 + nt * 16 + lc;
                b[nt] = *(const s8v*)&Bs[col * 64 + (((kk * 4 + quad) ^ (col & 7)) * 8)];
            }
            #pragma unroll
            for (int mt = 0; mt < 4; ++mt) {
                int row = wr * 64 + mt * 16 + lc;
                s8v a = *(const s8v*)&As[row * 64 + (((kk * 4 + quad) ^ (row & 7)) * 8)];
                acc[mt][0] = __builtin_amdgcn_mfma_f32_16x16x32_bf16(a, b[0], acc[mt][0], 0, 0, 0);
                acc[mt][1] = __builtin_amdgcn_mfma_f32_16x16x32_bf16(a, b[1], acc[mt][1], 0, 0, 0);
            }
        }
        __syncthreads();
    }

    #pragma unroll
    for (int mt = 0; mt < 4; ++mt)
        #pragma unroll
        for (int nt = 0; nt < 2; ++nt)
            #pragma unroll
            for (int i = 0; i < 4; ++i) {
                int row = bm * 128 + wr * 64 + mt * 16 + quad * 4 + i;
                int col = bn * 64 + wc * 32 + nt * 16 + lc;
                float v = acc[mt][nt][i];
                if (EPI == 3) {
                    if (col < E_) C[(size_t)row * E_ + col] = __float2bfloat16(v);
                    else          C2[(size_t)row * E_ + (col - E_)] = __float2bfloat16(v);
                } else {
                    C[(size_t)row * E_ + col] = __float2bfloat16(v);
                }
            }
}

// ---------------- GEMM v3: 64x64 tile, grid 64x12 = 768 blocks (3/CU balanced) ----------------
// EPI 0: store  1: bias+residual  2: bias+gelu
template <int EPI>
__global__ __launch_bounds__(256, 4) void gemm3(const bf16* __restrict__ A,
                                                const bf16* __restrict__ Bt,
                                                bf16* __restrict__ C,
                                                const bf16* __restrict__ bias,
                                                const bf16* __restrict__ res) {
    __shared__ short As[64 * 64];
    __shared__ short Bs[64 * 64];
    const int bm = blockIdx.x, bn = blockIdx.y;
    const int tid = threadIdx.x;
    const int w = tid >> 6, l = tid & 63;
    const int wr = (w >> 1) * 32, wc = (w & 1) * 32;
    const int lc = l & 15, quad = l >> 4;
    const int srA = l >> 3, slot = l & 7;

    f4v acc[2][2] = {};

    for (int k0 = 0; k0 < E_; k0 += 64) {
        #pragma unroll
        for (int c = 0; c < 2; ++c) {
            int seg = w * 2 + c;
            int row = seg * 8 + srA;
            int kc = (slot ^ srA) * 8;
            async_copy16(A + (size_t)(bm * 64 + row) * E_ + k0 + kc, &As[seg * 512]);
            async_copy16(Bt + (size_t)(bn * 64 + row) * E_ + k0 + kc, &Bs[seg * 512]);
        }
        __syncthreads();

        #pragma unroll
        for (int kk = 0; kk < 2; ++kk) {
            s8v a[2], b[2];
            #pragma unroll
            for (int t = 0; t < 2; ++t) {
                int ar = wr + t * 16 + lc;
                a[t] = *(const s8v*)&As[ar * 64 + (((kk * 4 + quad) ^ (ar & 7)) * 8)];
                int bc = wc + t * 16 + lc;
                b[t] = *(const s8v*)&Bs[bc * 64 + (((kk * 4 + quad) ^ (bc & 7)) * 8)];
            }
            acc[0][0] = __builtin_amdgcn_mfma_f32_16x16x32_bf16(a[0], b[0], acc[0][0], 0, 0, 0);
            acc[0][1] = __builtin_amdgcn_mfma_f32_16x16x32_bf16(a[0], b[1], acc[0][1], 0, 0, 0);
            acc[1][0] = __builtin_amdgcn_mfma_f32_16x16x32_bf16(a[1], b[0], acc[1][0], 0, 0, 0);
            acc[1][1] = __builtin_amdgcn_mfma_f32_16x16x32_bf16(a[1], b[1], acc[1][1], 0, 0, 0);
        }
        __syncthreads();
    }

    #pragma unroll
    for (int mt = 0; mt < 2; ++mt)
        #pragma unroll
        for (int nt = 0; nt < 2; ++nt)
            #pragma unroll
            for (int i = 0; i < 4; ++i) {
                int row = bm * 64 + wr + mt * 16 + quad * 4 + i;
                int col = bn * 64 + wc + nt * 16 + lc;
                float v = acc[mt][nt][i];
                if (EPI == 1)
                    v += __bfloat162float(bias[col]) + __bfloat162float(res[(size_t)row * E_ + col]);
                if (EPI == 2) {
                    v += __bfloat162float(bias[col]);
                    v = 0.5f * v * (1.0f + erff(v * 0.70710678118654752f));
                }
                C[(size_t)row * E_ + col] = __float2bfloat16(v);
            }
}

// ---------------- fused flash attention; grid (bh=96, qt=8) for CU balance ----------------
template <bool CAUSAL>
__global__ __launch_bounds__(256) void attn_kernel(const bf16* __restrict__ Q,
                                                   const bf16* __restrict__ Kx,
                                                   bf16* __restrict__ O,
                                                   const int* __restrict__ vlen) {
    __shared__ short qs[64 * 72];
    __shared__ short ks[64 * 72];
    __shared__ short kts[64 * 72];
    __shared__ short ps[64 * 72];

    const int bh = blockIdx.x;                 // 0..95, varies fastest
    const int qt = blockIdx.y;                 // 0..7
    const int h = bh % H_, b = bh / H_;
    const int tid = threadIdx.x, w = tid >> 6, l = tid & 63;
    const int lr = (l >> 4) * 4, lc = l & 15, ko = (l >> 4) * 8;

    for (int c = tid * 2; c < tid * 2 + 2; ++c) {
        int row = c >> 3, dc = (c & 7) * 8;
        const bf16* src = Q + (((size_t)(b * S_ + qt * 64 + row) * H_ + h) * HD_ + dc);
        *(s8v*)&qs[row * 72 + dc] = *(const s8v*)src;
    }

    const int valid = CAUSAL ? S_ : vlen[b];
    const int kmax = CAUSAL ? (qt + 1) : ((valid + 63) >> 6);

    float m_i[4], l_i[4];
    for (int i = 0; i < 4; i++) { m_i[i] = -3.0e38f; l_i[i] = 0.0f; }
    f4v o_acc[4] = {};
    __syncthreads();

    for (int kt = 0; kt < kmax; ++kt) {
        for (int c = tid * 2; c < tid * 2 + 2; ++c) {
            int row = c >> 3, dc = (c & 7) * 8;
            const bf16* src = Kx + (((size_t)(b * S_ + kt * 64 + row) * H_ + h) * HD_ + dc);
            s8v v = *(const s8v*)src;
            *(s8v*)&ks[row * 72 + dc] = v;
            #pragma unroll
            for (int j = 0; j < 8; j++) kts[(dc + j) * 72 + row] = v[j];
        }
        __syncthreads();

        f4v sacc[4] = {};
        s8v aq0 = *(const s8v*)&qs[(w * 16 + lc) * 72 + ko];
        s8v aq1 = *(const s8v*)&qs[(w * 16 + lc) * 72 + 32 + ko];
        #pragma unroll
        for (int nt = 0; nt < 4; nt++) {
            s8v bk0 = *(const s8v*)&ks[(nt * 16 + lc) * 72 + ko];
            s8v bk1 = *(const s8v*)&ks[(nt * 16 + lc) * 72 + 32 + ko];
            sacc[nt] = __builtin_amdgcn_mfma_f32_16x16x32_bf16(aq0, bk0, sacc[nt], 0, 0, 0);
            sacc[nt] = __builtin_amdgcn_mfma_f32_16x16x32_bf16(aq1, bk1, sacc[nt], 0, 0, 0);
        }

        #pragma unroll
        for (int i = 0; i < 4; i++) {
            int qabs = qt * 64 + w * 16 + lr + i;
            float sv[4];
            float mx = -3.0e38f;
            #pragma unroll
            for (int nt = 0; nt < 4; nt++) {
                int kabs = kt * 64 + nt * 16 + lc;
                float s = sacc[nt][i] * 0.125f;
                bool ok = CAUSAL ? (kabs <= qabs) : (kabs < valid);
                sv[nt] = ok ? s : -1.0e4f;
                mx = fmaxf(mx, sv[nt]);
            }
            #pragma unroll
            for (int off = 1; off < 16; off <<= 1) mx = fmaxf(mx, __shfl_xor(mx, off));
            float mnew = fmaxf(m_i[i], mx);
            float alpha = __expf(m_i[i] - mnew);
            float psum = 0.0f;
            #pragma unroll
            for (int nt = 0; nt < 4; nt++) {
                float p = __expf(sv[nt] - mnew);
                psum += p;
                *(bf16*)&ps[(w * 16 + lr + i) * 72 + nt * 16 + lc] = __float2bfloat16(p);
            }
            #pragma unroll
            for (int off = 1; off < 16; off <<= 1) psum += __shfl_xor(psum, off);
            l_i[i] = l_i[i] * alpha + psum;
            m_i[i] = mnew;
            #pragma unroll
            for (int dt = 0; dt < 4; dt++) o_acc[dt][i] *= alpha;
        }
        __syncthreads();

        s8v ap0 = *(const s8v*)&ps[(w * 16 + lc) * 72 + ko];
        s8v ap1 = *(const s8v*)&ps[(w * 16 + lc) * 72 + 32 + ko];
        #pragma unroll
        for (int dt = 0; dt < 4; dt++) {
            s8v bv0 = *(const s8v*)&kts[(dt * 16 + lc) * 72 + ko];
            s8v bv1 = *(const s8v*)&kts[(dt * 16 + lc) * 72 + 32 + ko];
            o_acc[dt] = __builtin_amdgcn_mfma_f32_16x16x32_bf16(ap0, bv0, o_acc[dt], 0, 0, 0);
            o_acc[dt] = __builtin_amdgcn_mfma_f32_16x16x32_bf16(ap1, bv1, o_acc[dt], 0, 0, 0);
        }
        __syncthreads();
    }

    #pragma unroll
    for (int dt = 0; dt < 4; dt++)
        #pragma unroll
        for (int i = 0; i < 4; i++) {
            int q = qt * 64 + w * 16 + lr + i;
            int d = dt * 16 + lc;
            float v = o_acc[dt][i] / l_i[i];
            O[((size_t)(b * S_ + q) * H_ + h) * HD_ + d] = __float2bfloat16(v);
        }
}

// ---------------- LayerNorm v2: 1 wave/row, 4 rows/block, no barriers ----------------
__global__ __launch_bounds__(256) void ln2_kernel(const bf16* __restrict__ X,
                                                  const bf16* __restrict__ wv,
                                                  const bf16* __restrict__ bv,
                                                  bf16* __restrict__ outb,
                                                  float* __restrict__ outf,
                                                  const int* __restrict__ flag) {
    const int row = blockIdx.x * 4 + (threadIdx.x >> 6);
    const int l = threadIdx.x & 63;
    const bf16* xr = X + (size_t)row * E_;
    // lane l covers cols [l*8, l*8+8) and [512 + l*4, 512 + l*4 + 4)
    s8v v8 = *(const s8v*)(xr + l * 8);
    s4v v4 = *(const s4v*)(xr + 512 + l * 4);
    float x[12];
    #pragma unroll
    for (int j = 0; j < 8; ++j) x[j] = sh2f(v8[j]);
    #pragma unroll
    for (int j = 0; j < 4; ++j) x[8 + j] = sh2f(v4[j]);
    float s = 0.f, ss = 0.f;
    #pragma unroll
    for (int j = 0; j < 12; ++j) { s += x[j]; ss += x[j] * x[j]; }
    #pragma unroll
    for (int off = 1; off < 64; off <<= 1) {
        s += __shfl_xor(s, off);
        ss += __shfl_xor(ss, off);
    }
    float mu = s * (1.0f / E_);
    float var = ss * (1.0f / E_) - mu * mu;
    float rstd = rsqrtf(fmaxf(var, 0.0f) + 1e-12f);
    const bool f32out = (outf != nullptr) && (*flag != 0);
    #pragma unroll
    for (int j = 0; j < 12; ++j) {
        int c = (j < 8) ? (l * 8 + j) : (512 + l * 4 + (j - 8));
        float v = (x[j] - mu) * rstd * __bfloat162float(wv[c]) + __bfloat162float(bv[c]);
        if (f32out) outf[(size_t)row * E_ + c] = v;
        else        outb[(size_t)row * E_ + c] = __float2bfloat16(v);
    }
}

extern "C" void kernel_launch(void* const* d_in, const int* in_sizes, int n_in,
                              void* d_out, int out_size, void* d_ws, size_t ws_size,
                              hipStream_t stream) {
    const void* X = d_in[0];
    const void* enc = d_in[1];
    const int* vlen = (const int*)d_in[2];

    char* ws = (char*)d_ws;
    int* flag = (int*)ws;
    bf16* vecs = (bf16*)(ws + 256);
    char* wbase = ws + 16384;
    const size_t WSZ = (size_t)E_ * E_ * sizeof(bf16);
    bf16* wk1 = (bf16*)(wbase + 0 * WSZ);   // wk1|wq1 contiguous = N=1536 Bt
    bf16* wq1 = (bf16*)(wbase + 1 * WSZ);
    bf16* wk2 = (bf16*)(wbase + 2 * WSZ);
    bf16* wq2 = (bf16*)(wbase + 3 * WSZ);
    bf16* p1t = (bf16*)(wbase + 4 * WSZ);
    bf16* p2t = (bf16*)(wbase + 5 * WSZ);
    bf16* f1t = (bf16*)(wbase + 6 * WSZ);
    bf16* f2t = (bf16*)(wbase + 7 * WSZ);
    const size_t ASZ = (size_t)M_ * E_ * sizeof(bf16);
    char* abase = wbase + 8 * WSZ;
    bf16* Xc   = (bf16*)(abase + 0 * ASZ);
    bf16* ENCc = (bf16*)(abase + 1 * ASZ);
    bf16* A0 = (bf16*)(abase + 2 * ASZ);
    bf16* A1 = (bf16*)(abase + 3 * ASZ);
    bf16* A2 = (bf16*)(abase + 4 * ASZ);
    bf16* A3 = (bf16*)(abase + 5 * ASZ);

    bf16* bias1 = vecs + 0 * E_;
    bf16* lw1   = vecs + 1 * E_;
    bf16* lb1   = vecs + 2 * E_;
    bf16* bias2 = vecs + 3 * E_;
    bf16* lw2   = vecs + 4 * E_;
    bf16* lb2   = vecs + 5 * E_;
    bf16* fb1   = vecs + 6 * E_;
    bf16* fb2   = vecs + 7 * E_;
    bf16* lw3   = vecs + 8 * E_;
    bf16* lb3   = vecs + 9 * E_;

    detect_kernel<<<1, 256, 0, stream>>>((const unsigned int*)X, flag);

    conv2_kernel<<<dim3(M_ * E_ / 1024, 2), 256, 0, stream>>>(X, enc, Xc, ENCc, flag);

    P9 rp;
    rp.s[0] = d_in[3];  rp.d[0] = wk1;    // permute slots 0..3
    rp.s[1] = d_in[4];  rp.d[1] = wq1;
    rp.s[2] = d_in[9];  rp.d[2] = wk2;
    rp.s[3] = d_in[10]; rp.d[3] = wq2;
    rp.s[4] = d_in[5];  rp.d[4] = p1t;    // transpose slots 4..7
    rp.s[5] = d_in[11]; rp.d[5] = p2t;
    rp.s[6] = d_in[15]; rp.d[6] = f1t;
    rp.s[7] = d_in[17]; rp.d[7] = f2t;
    rp.vs[0] = d_in[6];  rp.vd[0] = bias1;
    rp.vs[1] = d_in[7];  rp.vd[1] = lw1;
    rp.vs[2] = d_in[8];  rp.vd[2] = lb1;
    rp.vs[3] = d_in[12]; rp.vd[3] = bias2;
    rp.vs[4] = d_in[13]; rp.vd[4] = lw2;
    rp.vs[5] = d_in[14]; rp.vd[5] = lb2;
    rp.vs[6] = d_in[16]; rp.vd[6] = fb1;
    rp.vs[7] = d_in[18]; rp.vd[7] = fb2;
    rp.vs[8] = d_in[19]; rp.vd[8] = lw3;
    rp.vs[9] = d_in[20]; rp.vd[9] = lb3;
    repack_kernel<<<dim3(12, 12, 9), 256, 0, stream>>>(rp, flag);

    // self-attention block
    gemm2<3><<<dim3(32, 24), 256, 0, stream>>>(Xc, wk1, A0, A1, nullptr, nullptr);  // kx1->A0, qx1->A1
    attn_kernel<true><<<dim3(96, 8), 256, 0, stream>>>(A1, A0, A2, nullptr);
    gemm3<1><<<dim3(64, 12), 256, 0, stream>>>(A2, p1t, A3, bias1, Xc);             // X2 + X
    ln2_kernel<<<M_ / 4, 256, 0, stream>>>(A3, lw1, lb1, A0, nullptr, flag);        // Y -> A0
    // cross-attention block
    gemm3<0><<<dim3(64, 12), 256, 0, stream>>>(ENCc, wk2, A1, nullptr, nullptr);    // kx2
    gemm3<0><<<dim3(64, 12), 256, 0, stream>>>(A0, wq2, A2, nullptr, nullptr);      // qx2
    attn_kernel<false><<<dim3(96, 8), 256, 0, stream>>>(A2, A1, A3, vlen);
    gemm3<1><<<dim3(64, 12), 256, 0, stream>>>(A3, p2t, A1, bias2, A0);             // Y2 + Y
    ln2_kernel<<<M_ / 4, 256, 0, stream>>>(A1, lw2, lb2, A2, nullptr, flag);        // Z -> A2
    // FFN
    gemm3<2><<<dim3(64, 12), 256, 0, stream>>>(A2, f1t, A3, fb1, nullptr);          // gelu
    gemm3<1><<<dim3(64, 12), 256, 0, stream>>>(A3, f2t, A1, fb2, A2);               // F + Z
    ln2_kernel<<<M_ / 4, 256, 0, stream>>>(A1, lw3, lb3, (bf16*)d_out, (float*)d_out, flag);
}